// Round 8
// baseline (531.057 us; speedup 1.0000x reference)
//
#include <hip/hip_runtime.h>
#include <cstddef>
#include <cstdint>

#define N_IN  128
#define N_HID 128
#define N_OUT 64

typedef unsigned short ushort;
typedef unsigned int uint;
using short8 = __attribute__((ext_vector_type(8))) short;
using f32x4  = __attribute__((ext_vector_type(4))) float;

__device__ __forceinline__ ushort f2b(float f) {
  uint u = __builtin_bit_cast(uint, f);
  uint r = (u + 0x7fffu + ((u >> 16) & 1u)) >> 16;   // RNE
  return (ushort)r;
}
__device__ __forceinline__ float b2f(ushort u) {
  return __builtin_bit_cast(float, ((uint)u) << 16);
}

// ================= CSR build =================

__global__ void count_deg_kernel(const int* __restrict__ ei, int* __restrict__ deg, int E) {
  int e = blockIdx.x * 256 + threadIdx.x;
  if (e < E) atomicAdd(&deg[ei[E + e]], 1);
}

__global__ __launch_bounds__(256) void scanA_kernel(const int* __restrict__ deg,
                                                    int* __restrict__ bsum, int n) {
  int i = blockIdx.x * 256 + threadIdx.x;
  int v = (i < n) ? deg[i] : 0;
#pragma unroll
  for (int off = 32; off > 0; off >>= 1) v += __shfl_xor(v, off, 64);
  __shared__ int ws[4];
  int lane = threadIdx.x & 63, wid = threadIdx.x >> 6;
  if (lane == 0) ws[wid] = v;
  __syncthreads();
  if (threadIdx.x == 0) bsum[blockIdx.x] = ws[0] + ws[1] + ws[2] + ws[3];
}

__global__ __launch_bounds__(256) void scanB_kernel(int* __restrict__ bsum, int nb) {
  int tid = threadIdx.x;
  int c = (nb + 255) >> 8;
  int st = tid * c, en = min(st + c, nb);
  int s = 0;
  for (int i = st; i < en; ++i) s += bsum[i];
  int lane = tid & 63, wid = tid >> 6;
  int incl = s;
#pragma unroll
  for (int off = 1; off < 64; off <<= 1) {
    int t = __shfl_up(incl, off, 64);
    if (lane >= off) incl += t;
  }
  __shared__ int ws[4];
  if (lane == 63) ws[wid] = incl;
  __syncthreads();
  int wbase = 0;
  for (int w = 0; w < wid; ++w) wbase += ws[w];
  int ex = wbase + incl - s;
  for (int i = st; i < en; ++i) {
    int d = bsum[i];
    bsum[i] = ex;
    ex += d;
  }
}

__global__ __launch_bounds__(256) void scanC_kernel(const int* __restrict__ deg,
                                                    const int* __restrict__ bsum,
                                                    int* __restrict__ rowptr,
                                                    float* __restrict__ dis, int n) {
  int i = blockIdx.x * 256 + threadIdx.x;
  int d = (i < n) ? deg[i] : 0;
  int lane = threadIdx.x & 63, wid = threadIdx.x >> 6;
  int incl = d;
#pragma unroll
  for (int off = 1; off < 64; off <<= 1) {
    int t = __shfl_up(incl, off, 64);
    if (lane >= off) incl += t;
  }
  __shared__ int ws[4];
  if (lane == 63) ws[wid] = incl;
  __syncthreads();
  int wbase = 0;
  for (int w = 0; w < wid; ++w) wbase += ws[w];
  int ex = bsum[blockIdx.x] + wbase + incl - d;
  if (i < n) {
    rowptr[i] = ex;
    dis[i] = (d > 0) ? rsqrtf((float)d) : 0.0f;
    if (i == n - 1) rowptr[n] = ex + d;
  }
}

// (src, dis[src]) entries: 8B payload costs the same line-granular write
// amplification as 4B (measured R3 vs R4), so the weight rides free.
__global__ void fill_csr_kernel(const int* __restrict__ ei, int* __restrict__ cursor,
                                int2* __restrict__ ew, const float* __restrict__ dis, int E) {
  int e = blockIdx.x * 256 + threadIdx.x;
  if (e >= E) return;
  int s = ei[e];
  int d = ei[E + e];
  int pos = atomicAdd(&cursor[d], 1);
  ew[pos] = make_int2(s, __builtin_bit_cast(int, dis[s]));
}

// ================= fp32 -> bf16 convert into sliced [fb][node][32] layout =================

__global__ __launch_bounds__(256) void cvt_bf16_kernel(const float* __restrict__ in,
                                                       ushort* __restrict__ xb, int n, int n4) {
  int i = blockIdx.x * 256 + threadIdx.x;
  if (i >= n4) return;
  int node = i >> 5;       // 32 float4 per 128-wide row
  int fg = i & 31;         // feature group of 4; slice = fg>>3
  float4 v = reinterpret_cast<const float4*>(in)[i];
  ushort4 o;
  o.x = f2b(v.x); o.y = f2b(v.y); o.z = f2b(v.z); o.w = f2b(v.w);
  size_t dst = (((size_t)(fg >> 3) * n + node) << 5) + (fg & 7) * 4;
  *reinterpret_cast<ushort4*>(xb + dst) = o;
}

// ================= W pack into MFMA B-fragment order =================
// pw[(k*4+kk)*CT + ct][lane][j] = W[k][kk*32 + (lane>>4)*8 + j][ct*16 + (lane&15)]

template <int FOUT>
__global__ __launch_bounds__(256) void pack_w_kernel(const float* __restrict__ W,
                                                     ushort* __restrict__ pw) {
  constexpr int CT = FOUT / 16;
  int t = blockIdx.x * 256 + threadIdx.x;
  if (t >= 4 * 4 * CT * 64) return;
  int lane = t & 63;
  int g = t >> 6;
  int ct = g % CT;
  int kk = (g / CT) % 4;
  int k  = g / (CT * 4);
  int col = ct * 16 + (lane & 15);
  int krow0 = kk * 32 + (lane >> 4) * 8;
  ushort* dst = pw + (size_t)t * 8;
  const float* src = W + ((size_t)k * 128 + krow0) * FOUT + col;
#pragma unroll
  for (int j = 0; j < 8; ++j) dst[j] = f2b(src[(size_t)j * FOUT]);
}

// ================= sparse propagation, L2-sliced =================
// Features sliced [fb][node][32], fb in [0,4). Slice = 3.2MB -> fits a 4MiB XCD L2.
// fb = blockIdx&3 under the bid%8->XCD round-robin pins slice fb to XCDs {fb, fb+4}.
// One wave per (node, slice): 8 lanes per edge x uint2 (4 feats) -> one load instr
// fetches 8 edges x 64B = 512B (same bytes/instr as the unsliced prop).
// Cross-edge reduce: shfl_xor 8/16/32. 16 edges in flight per wave.
// out_i = -dis_i * sum_e w_e*in[src_e]   (sub==nullptr)
// out_i = 2*(-dis_i*sum) - sub_i         (sub!=nullptr)

__global__ __launch_bounds__(256) void prop_kernel(
    const ushort* __restrict__ in, const ushort* __restrict__ sub,
    ushort* __restrict__ out,
    const int* __restrict__ rowptr, const int2* __restrict__ ew,
    const float* __restrict__ dis, int n) {
  int fb = blockIdx.x & 3;
  int node = (blockIdx.x >> 2) * 4 + (threadIdx.x >> 6);
  if (node >= n) return;
  int lane = threadIdx.x & 63;
  int q = lane >> 3;        // edge slot within batch of 8
  int fl = lane & 7;        // 4-feature group within the 32-feature slice
  const ushort* base = in + (((size_t)fb * n) << 5);
  int s = rowptr[node];
  int e = rowptr[node + 1];
  float a0 = 0.f, a1 = 0.f, a2 = 0.f, a3 = 0.f;
  for (int i = s; i < e; i += 16) {
    int i0 = i + q, i1 = i + 8 + q;
    int2 p0 = ew[min(i0, e - 1)];
    int2 p1 = ew[min(i1, e - 1)];
    uint2 v0 = *reinterpret_cast<const uint2*>(base + (((size_t)p0.x) << 5) + (fl << 2));
    uint2 v1 = *reinterpret_cast<const uint2*>(base + (((size_t)p1.x) << 5) + (fl << 2));
    float w0 = (i0 < e) ? __builtin_bit_cast(float, p0.y) : 0.f;
    float w1 = (i1 < e) ? __builtin_bit_cast(float, p1.y) : 0.f;
    a0 = fmaf(w0, b2f((ushort)v0.x), a0);
    a1 = fmaf(w0, b2f((ushort)(v0.x >> 16)), a1);
    a2 = fmaf(w0, b2f((ushort)v0.y), a2);
    a3 = fmaf(w0, b2f((ushort)(v0.y >> 16)), a3);
    a0 = fmaf(w1, b2f((ushort)v1.x), a0);
    a1 = fmaf(w1, b2f((ushort)(v1.x >> 16)), a1);
    a2 = fmaf(w1, b2f((ushort)v1.y), a2);
    a3 = fmaf(w1, b2f((ushort)(v1.y >> 16)), a3);
  }
#pragma unroll
  for (int off = 8; off < 64; off <<= 1) {
    a0 += __shfl_xor(a0, off, 64);
    a1 += __shfl_xor(a1, off, 64);
    a2 += __shfl_xor(a2, off, 64);
    a3 += __shfl_xor(a3, off, 64);
  }
  if (q == 0) {
    size_t ro = (((size_t)fb * n + node) << 5) + (fl << 2);
    float sc = -dis[node];
    float r0, r1, r2, r3;
    if (sub != nullptr) {
      uint2 sv = *reinterpret_cast<const uint2*>(sub + ro);
      float t = 2.f * sc;
      r0 = fmaf(t, a0, -b2f((ushort)sv.x));
      r1 = fmaf(t, a1, -b2f((ushort)(sv.x >> 16)));
      r2 = fmaf(t, a2, -b2f((ushort)sv.y));
      r3 = fmaf(t, a3, -b2f((ushort)(sv.y >> 16)));
    } else {
      r0 = sc * a0; r1 = sc * a1; r2 = sc * a2; r3 = sc * a3;
    }
    uint2 o;
    o.x = (uint)f2b(r0) | ((uint)f2b(r1) << 16);
    o.y = (uint)f2b(r2) | ((uint)f2b(r3) << 16);
    *reinterpret_cast<uint2*>(out + ro) = o;
  }
}

// ================= MFMA Chebyshev GEMM (sliced-A inputs) =================
// out = epilogue( [A0|A1|A2|A3] @ packedW + bias ); A*: sliced [fb][n][32] bf16.
// The 32-feat slice aligns exactly with the MFMA K-step: kk selects the slice.
// 2 waves/block, 2 row-tiles of 16 per wave. D: col=lane&15, row=(lane>>4)*4+reg.
// FUSE_LSM (FOUT=64): in-register log-softmax, fp32 row-major output.

template <int FOUT, bool RELU, bool OUT_BF16, bool FUSE_LSM>
__global__ __launch_bounds__(128) void mfma_gemm_kernel(
    const ushort* __restrict__ A0, const ushort* __restrict__ A1,
    const ushort* __restrict__ A2, const ushort* __restrict__ A3,
    const ushort* __restrict__ pw, const float* __restrict__ bias,
    void* __restrict__ outv, int n) {
  constexpr int CT = FOUT / 16;
  int wid = threadIdx.x >> 6;
  int lane = threadIdx.x & 63;
  int rbase = (blockIdx.x * 2 + wid) * 32;
  if (rbase >= n) return;                 // n % 16 == 0
  bool t1ok = (rbase + 16) < n;
  const ushort* Ap[4] = {A0, A1, A2, A3};
  f32x4 acc[2][CT];
#pragma unroll
  for (int t = 0; t < 2; ++t)
#pragma unroll
    for (int c = 0; c < CT; ++c) acc[t][c] = (f32x4){0.f, 0.f, 0.f, 0.f};
  int rl = rbase + (lane & 15);
  int qo = (lane >> 4) * 8;
#pragma unroll
  for (int k = 0; k < 4; ++k) {
    const ushort* A = Ap[k];
#pragma unroll
    for (int kk = 0; kk < 4; ++kk) {
      short8 a0 = *reinterpret_cast<const short8*>(A + (((size_t)kk * n + rl) << 5) + qo);
      short8 a1 = {};
      if (t1ok)
        a1 = *reinterpret_cast<const short8*>(A + (((size_t)kk * n + rl + 16) << 5) + qo);
      const ushort* B = pw + ((size_t)((k * 4 + kk) * CT) * 64 + lane) * 8;
#pragma unroll
      for (int c = 0; c < CT; ++c) {
        short8 b = *reinterpret_cast<const short8*>(B + (size_t)c * 64 * 8);
        acc[0][c] = __builtin_amdgcn_mfma_f32_16x16x32_bf16(a0, b, acc[0][c], 0, 0, 0);
        acc[1][c] = __builtin_amdgcn_mfma_f32_16x16x32_bf16(a1, b, acc[1][c], 0, 0, 0);
      }
    }
  }
  int colb = lane & 15;
  int rsub = (lane >> 4) * 4;
#pragma unroll
  for (int t = 0; t < 2; ++t) {
    int row0 = rbase + t * 16;
    if (row0 >= n) continue;
    if (FUSE_LSM) {
#pragma unroll
      for (int r = 0; r < 4; ++r) {
        int row = row0 + rsub + r;
        float v[CT];
        float m = -1e30f;
#pragma unroll
        for (int c = 0; c < CT; ++c) {
          v[c] = acc[t][c][r] + bias[c * 16 + colb];
          m = fmaxf(m, v[c]);
        }
#pragma unroll
        for (int off = 1; off < 16; off <<= 1) m = fmaxf(m, __shfl_xor(m, off, 64));
        float s = 0.f;
#pragma unroll
        for (int c = 0; c < CT; ++c) s += __expf(v[c] - m);
#pragma unroll
        for (int off = 1; off < 16; off <<= 1) s += __shfl_xor(s, off, 64);
        float ls = logf(s) + m;
#pragma unroll
        for (int c = 0; c < CT; ++c)
          reinterpret_cast<float*>(outv)[(size_t)row * FOUT + c * 16 + colb] = v[c] - ls;
      }
    } else {
#pragma unroll
      for (int c = 0; c < CT; ++c) {
        int col = c * 16 + colb;
        float bv = bias[col];
#pragma unroll
        for (int r = 0; r < 4; ++r) {
          int row = row0 + rsub + r;
          float v = acc[t][c][r] + bv;
          if (RELU) v = fmaxf(v, 0.f);
          // sliced write: slice = col>>5, within-slice = col&31
          size_t oi = (((size_t)(col >> 5) * n + row) << 5) + (col & 31);
          if (OUT_BF16) reinterpret_cast<ushort*>(outv)[oi] = f2b(v);
          else          reinterpret_cast<float*>(outv)[oi] = v;
        }
      }
    }
  }
}

// ================= launcher =================

extern "C" void kernel_launch(void* const* d_in, const int* in_sizes, int n_in,
                              void* d_out, int out_size, void* d_ws, size_t ws_size,
                              hipStream_t stream) {
  const float* x  = (const float*)d_in[0];
  const int*   ei = (const int*)d_in[1];
  const float* W1 = (const float*)d_in[2];
  const float* b1 = (const float*)d_in[3];
  const float* W2 = (const float*)d_in[4];
  const float* b2 = (const float*)d_in[5];
  float* out = (float*)d_out;

  const int N = in_sizes[0] / N_IN;
  const int E = in_sizes[1] / 2;
  const int NB = (N + 255) / 256;

  char* base = (char*)d_ws;
  size_t off = 0;
  auto alloc = [&](size_t bytes) -> void* {
    void* p = base + off;
    off = (off + bytes + 255) & ~(size_t)255;
    return p;
  };
  int*    deg    = (int*)alloc((size_t)N * 4);
  int*    rowptr = (int*)alloc((size_t)(N + 1) * 4);
  int*    cursor = (int*)alloc((size_t)N * 4);
  int*    bsum   = (int*)alloc((size_t)NB * 4);
  int2*   ew     = (int2*)alloc((size_t)E * 8);
  float*  dis    = (float*)alloc((size_t)N * 4);
  size_t  fsz    = (size_t)N * N_IN * 2;
  ushort* S1 = (ushort*)alloc(fsz);
  ushort* S2 = (ushort*)alloc(fsz);
  ushort* S3 = (ushort*)alloc(fsz);
  ushort* S4 = (ushort*)alloc(fsz);
  ushort* S5 = (ushort*)alloc(fsz);
  ushort* pw1 = (ushort*)alloc((size_t)4 * N_IN * N_HID * 2);
  ushort* pw2 = (ushort*)alloc((size_t)4 * N_HID * N_OUT * 2);

  // buffer lifetimes: layer1 {xb,T1,T2,T3} -> GEMM1 -> H; xb dead after GEMM1.
  ushort *xb = S1, *T1 = S2, *T2 = S3, *T3 = S4, *H = S5;
  ushort *U1 = S1, *U2 = S2, *U3 = S3;   // reuse: xb dead, T1 dead after U2, T2 after U3

  hipMemsetAsync(deg, 0, (size_t)N * 4, stream);
  count_deg_kernel<<<(E + 255) / 256, 256, 0, stream>>>(ei, deg, E);
  scanA_kernel<<<NB, 256, 0, stream>>>(deg, bsum, N);
  scanB_kernel<<<1, 256, 0, stream>>>(bsum, NB);
  scanC_kernel<<<NB, 256, 0, stream>>>(deg, bsum, rowptr, dis, N);
  hipMemcpyAsync(cursor, rowptr, (size_t)N * 4, hipMemcpyDeviceToDevice, stream);
  fill_csr_kernel<<<(E + 255) / 256, 256, 0, stream>>>(ei, cursor, ew, dis, E);

  int n4 = N * N_IN / 4;
  cvt_bf16_kernel<<<(n4 + 255) / 256, 256, 0, stream>>>(x, xb, N, n4);
  pack_w_kernel<N_HID><<<(4 * 4 * (N_HID / 16) * 64 + 255) / 256, 256, 0, stream>>>(W1, pw1);
  pack_w_kernel<N_OUT><<<(4 * 4 * (N_OUT / 16) * 64 + 255) / 256, 256, 0, stream>>>(W2, pw2);

  int pgrid = 4 * ((N + 3) / 4);    // fb = bid&3 -> XCD-pinned slices
  int ggrid = (N + 63) / 64;
  // layer 1: Tx0 = x
  prop_kernel<<<pgrid, 256, 0, stream>>>(xb, nullptr, T1, rowptr, ew, dis, N);
  prop_kernel<<<pgrid, 256, 0, stream>>>(T1, xb,      T2, rowptr, ew, dis, N);
  prop_kernel<<<pgrid, 256, 0, stream>>>(T2, T1,      T3, rowptr, ew, dis, N);
  mfma_gemm_kernel<N_HID, true, true, false><<<ggrid, 128, 0, stream>>>(
      xb, T1, T2, T3, pw1, b1, H, N);
  // layer 2: Tx0 = H
  prop_kernel<<<pgrid, 256, 0, stream>>>(H,  nullptr, U1, rowptr, ew, dis, N);
  prop_kernel<<<pgrid, 256, 0, stream>>>(U1, H,       U2, rowptr, ew, dis, N);
  prop_kernel<<<pgrid, 256, 0, stream>>>(U2, U1,      U3, rowptr, ew, dis, N);
  mfma_gemm_kernel<N_OUT, false, false, true><<<ggrid, 128, 0, stream>>>(
      H, U1, U2, U3, pw2, b2, out, N);
}

// Round 9
// 348.287 us; speedup vs baseline: 1.5248x; 1.5248x over previous
//
#include <hip/hip_runtime.h>
#include <cstddef>
#include <cstdint>

#define N_IN  128
#define N_HID 128
#define N_OUT 64

typedef unsigned short ushort;
typedef unsigned int uint;
using short8 = __attribute__((ext_vector_type(8))) short;
using f32x4  = __attribute__((ext_vector_type(4))) float;

__device__ __forceinline__ ushort f2b(float f) {
  uint u = __builtin_bit_cast(uint, f);
  uint r = (u + 0x7fffu + ((u >> 16) & 1u)) >> 16;   // RNE
  return (ushort)r;
}
__device__ __forceinline__ float b2f(ushort u) {
  return __builtin_bit_cast(float, ((uint)u) << 16);
}

// ================= CSR build =================

__global__ void count_deg_kernel(const int* __restrict__ ei, int* __restrict__ deg, int E) {
  int e = blockIdx.x * 256 + threadIdx.x;
  if (e < E) atomicAdd(&deg[ei[E + e]], 1);
}

__global__ __launch_bounds__(256) void scanA_kernel(const int* __restrict__ deg,
                                                    int* __restrict__ bsum, int n) {
  int i = blockIdx.x * 256 + threadIdx.x;
  int v = (i < n) ? deg[i] : 0;
#pragma unroll
  for (int off = 32; off > 0; off >>= 1) v += __shfl_xor(v, off, 64);
  __shared__ int ws[4];
  int lane = threadIdx.x & 63, wid = threadIdx.x >> 6;
  if (lane == 0) ws[wid] = v;
  __syncthreads();
  if (threadIdx.x == 0) bsum[blockIdx.x] = ws[0] + ws[1] + ws[2] + ws[3];
}

__global__ __launch_bounds__(256) void scanB_kernel(int* __restrict__ bsum, int nb) {
  int tid = threadIdx.x;
  int c = (nb + 255) >> 8;
  int st = tid * c, en = min(st + c, nb);
  int s = 0;
  for (int i = st; i < en; ++i) s += bsum[i];
  int lane = tid & 63, wid = tid >> 6;
  int incl = s;
#pragma unroll
  for (int off = 1; off < 64; off <<= 1) {
    int t = __shfl_up(incl, off, 64);
    if (lane >= off) incl += t;
  }
  __shared__ int ws[4];
  if (lane == 63) ws[wid] = incl;
  __syncthreads();
  int wbase = 0;
  for (int w = 0; w < wid; ++w) wbase += ws[w];
  int ex = wbase + incl - s;
  for (int i = st; i < en; ++i) {
    int d = bsum[i];
    bsum[i] = ex;
    ex += d;
  }
}

__global__ __launch_bounds__(256) void scanC_kernel(const int* __restrict__ deg,
                                                    const int* __restrict__ bsum,
                                                    int* __restrict__ rowptr,
                                                    float* __restrict__ dis, int n) {
  int i = blockIdx.x * 256 + threadIdx.x;
  int d = (i < n) ? deg[i] : 0;
  int lane = threadIdx.x & 63, wid = threadIdx.x >> 6;
  int incl = d;
#pragma unroll
  for (int off = 1; off < 64; off <<= 1) {
    int t = __shfl_up(incl, off, 64);
    if (lane >= off) incl += t;
  }
  __shared__ int ws[4];
  if (lane == 63) ws[wid] = incl;
  __syncthreads();
  int wbase = 0;
  for (int w = 0; w < wid; ++w) wbase += ws[w];
  int ex = bsum[blockIdx.x] + wbase + incl - d;
  if (i < n) {
    rowptr[i] = ex;
    dis[i] = (d > 0) ? rsqrtf((float)d) : 0.0f;
    if (i == n - 1) rowptr[n] = ex + d;
  }
}

__global__ void fill_csr_kernel(const int* __restrict__ ei, int* __restrict__ cursor,
                                int2* __restrict__ ew, const float* __restrict__ dis, int E) {
  int e = blockIdx.x * 256 + threadIdx.x;
  if (e >= E) return;
  int s = ei[e];
  int d = ei[E + e];
  int pos = atomicAdd(&cursor[d], 1);
  ew[pos] = make_int2(s, __builtin_bit_cast(int, dis[s]));
}

// ================= fp32 -> bf16 convert (row-major) =================

__global__ __launch_bounds__(256) void cvt_bf16_kernel(const float* __restrict__ in,
                                                       ushort* __restrict__ xb, int n4) {
  int i = blockIdx.x * 256 + threadIdx.x;
  if (i >= n4) return;
  float4 v = reinterpret_cast<const float4*>(in)[i];
  ushort4 o;
  o.x = f2b(v.x); o.y = f2b(v.y); o.z = f2b(v.z); o.w = f2b(v.w);
  reinterpret_cast<ushort4*>(xb)[i] = o;
}

// ================= W1 pack into MFMA B-fragment order =================
// pw[(k*4+kk)*CT + ct][lane][j] = W[k][kk*32 + (lane>>4)*8 + j][ct*16 + (lane&15)]

template <int FOUT>
__global__ __launch_bounds__(256) void pack_w_kernel(const float* __restrict__ W,
                                                     ushort* __restrict__ pw) {
  constexpr int CT = FOUT / 16;
  int t = blockIdx.x * 256 + threadIdx.x;
  if (t >= 4 * 4 * CT * 64) return;
  int lane = t & 63;
  int g = t >> 6;
  int ct = g % CT;
  int kk = (g / CT) % 4;
  int k  = g / (CT * 4);
  int col = ct * 16 + (lane & 15);
  int krow0 = kk * 32 + (lane >> 4) * 8;
  ushort* dst = pw + (size_t)t * 8;
  const float* src = W + ((size_t)k * 128 + krow0) * FOUT + col;
#pragma unroll
  for (int j = 0; j < 8; ++j) dst[j] = f2b(src[(size_t)j * FOUT]);
}

// ================= W2 combined pack (Horner coefficients) =================
// Wc[128][256] blocks: [W0-W2 | W1-3W3 | 2W2 | 4W3]; frag layout as above, K=128.

__global__ __launch_bounds__(256) void pack_w2c_kernel(const float* __restrict__ W,
                                                       ushort* __restrict__ pw) {
  int t = blockIdx.x * 256 + threadIdx.x;
  if (t >= 4 * 16 * 64) return;       // kk (4) x ct (16) x lane (64)
  int lane = t & 63;
  int g = t >> 6;
  int ct = g & 15;
  int kk = g >> 4;
  int col = ct * 16 + (lane & 15);    // 0..255
  int kb = col >> 6;                  // which combo block
  int cc = col & 63;
  int krow0 = kk * 32 + (lane >> 4) * 8;
  ushort* dst = pw + (size_t)t * 8;
#pragma unroll
  for (int j = 0; j < 8; ++j) {
    int r = krow0 + j;
    float w0 = W[((size_t)0 * 128 + r) * 64 + cc];
    float w1 = W[((size_t)1 * 128 + r) * 64 + cc];
    float w2 = W[((size_t)2 * 128 + r) * 64 + cc];
    float w3 = W[((size_t)3 * 128 + r) * 64 + cc];
    float v = (kb == 0) ? (w0 - w2)
            : (kb == 1) ? (w1 - 3.f * w3)
            : (kb == 2) ? (2.f * w2)
                        : (4.f * w3);
    dst[j] = f2b(v);
  }
}

// ================= sparse propagation, 128-wide (layer 1) =================
// out_i = -dis_i*sum_e w_e*in[src_e]      (sub==nullptr)
// out_i = 2*(-dis_i*sum) - sub_i          (sub!=nullptr)
// 2 nodes/wave, 32 lanes x uint2; unroll 8 -> 16 in-flight 256B gathers.

__global__ __launch_bounds__(256) void prop_kernel(
    const ushort* __restrict__ in, const ushort* __restrict__ sub,
    ushort* __restrict__ out,
    const int* __restrict__ rowptr, const int2* __restrict__ ew,
    const float* __restrict__ dis, int n) {
  int node = blockIdx.x * 8 + (threadIdx.x >> 5);
  if (node >= n) return;
  int hl = threadIdx.x & 31;
  int s = rowptr[node];
  int e = rowptr[node + 1];
  size_t ro = ((size_t)node << 7) + (hl << 2);
  uint2 sv = make_uint2(0u, 0u);
  if (sub != nullptr) sv = *reinterpret_cast<const uint2*>(sub + ro);
  float a0 = 0.f, a1 = 0.f, a2 = 0.f, a3 = 0.f;
  for (int i = s; i < e; i += 8) {
    int2 p[8];
#pragma unroll
    for (int j = 0; j < 8; ++j) {
      int idx = i + j;
      p[j] = ew[idx < e ? idx : e - 1];
    }
    uint2 v[8];
#pragma unroll
    for (int j = 0; j < 8; ++j)
      v[j] = *reinterpret_cast<const uint2*>(in + ((size_t)p[j].x << 7) + (hl << 2));
#pragma unroll
    for (int j = 0; j < 8; ++j) {
      float w = (i + j < e) ? __builtin_bit_cast(float, p[j].y) : 0.f;
      a0 = fmaf(w, b2f((ushort)v[j].x), a0);
      a1 = fmaf(w, b2f((ushort)(v[j].x >> 16)), a1);
      a2 = fmaf(w, b2f((ushort)v[j].y), a2);
      a3 = fmaf(w, b2f((ushort)(v[j].y >> 16)), a3);
    }
  }
  float sc = -dis[node];
  float r0, r1, r2, r3;
  if (sub != nullptr) {
    float t = 2.f * sc;
    r0 = fmaf(t, a0, -b2f((ushort)sv.x));
    r1 = fmaf(t, a1, -b2f((ushort)(sv.x >> 16)));
    r2 = fmaf(t, a2, -b2f((ushort)sv.y));
    r3 = fmaf(t, a3, -b2f((ushort)(sv.y >> 16)));
  } else {
    r0 = sc * a0; r1 = sc * a1; r2 = sc * a2; r3 = sc * a3;
  }
  uint2 o;
  o.x = (uint)f2b(r0) | ((uint)f2b(r1) << 16);
  o.y = (uint)f2b(r2) | ((uint)f2b(r3) << 16);
  *reinterpret_cast<uint2*>(out + ro) = o;
}

// ================= sparse propagation, 64-wide (layer-2 Horner chain) =================
// r_i = -dis_i * sum_e w_e*in[src_e] ;  result = r + aux_i  (Horner add folded in).
// F32OUT: write fp32 row-major (final A3 + C0 -> d_out). Else bf16.
// 2 nodes/wave, 32 lanes x uint (2 feats); unroll 8 -> 16 in-flight 128B gathers.

template <bool F32OUT>
__global__ __launch_bounds__(256) void prop64_kernel(
    const ushort* __restrict__ in, const ushort* __restrict__ aux,
    void* __restrict__ outv,
    const int* __restrict__ rowptr, const int2* __restrict__ ew,
    const float* __restrict__ dis, int n) {
  int node = blockIdx.x * 8 + (threadIdx.x >> 5);
  if (node >= n) return;
  int hl = threadIdx.x & 31;
  int s = rowptr[node];
  int e = rowptr[node + 1];
  float a0 = 0.f, a1 = 0.f;
  for (int i = s; i < e; i += 8) {
    int2 p[8];
#pragma unroll
    for (int j = 0; j < 8; ++j) {
      int idx = i + j;
      p[j] = ew[idx < e ? idx : e - 1];
    }
    uint v[8];
#pragma unroll
    for (int j = 0; j < 8; ++j)
      v[j] = *reinterpret_cast<const uint*>(in + ((size_t)p[j].x << 6) + (hl << 1));
#pragma unroll
    for (int j = 0; j < 8; ++j) {
      float w = (i + j < e) ? __builtin_bit_cast(float, p[j].y) : 0.f;
      a0 = fmaf(w, b2f((ushort)v[j]), a0);
      a1 = fmaf(w, b2f((ushort)(v[j] >> 16)), a1);
    }
  }
  float sc = -dis[node];
  size_t ro = ((size_t)node << 6) + (hl << 1);
  uint av = *reinterpret_cast<const uint*>(aux + ro);
  float r0 = fmaf(sc, a0, b2f((ushort)av));
  float r1 = fmaf(sc, a1, b2f((ushort)(av >> 16)));
  if (F32OUT) {
    float2 o = make_float2(r0, r1);
    *reinterpret_cast<float2*>(reinterpret_cast<float*>(outv) + ro) = o;
  } else {
    uint o = (uint)f2b(r0) | ((uint)f2b(r1) << 16);
    *reinterpret_cast<uint*>(reinterpret_cast<ushort*>(outv) + ro) = o;
  }
}

// ================= MFMA GEMM, layer 1 (4 A's, FOUT=128, relu, bf16 out) =================

template <int FOUT, bool RELU>
__global__ __launch_bounds__(128) void mfma_gemm_kernel(
    const ushort* __restrict__ A0, const ushort* __restrict__ A1,
    const ushort* __restrict__ A2, const ushort* __restrict__ A3,
    const ushort* __restrict__ pw, const float* __restrict__ bias,
    ushort* __restrict__ outb, int n) {
  constexpr int CT = FOUT / 16;
  int wid = threadIdx.x >> 6;
  int lane = threadIdx.x & 63;
  int rbase = (blockIdx.x * 2 + wid) * 32;
  if (rbase >= n) return;                 // n % 16 == 0
  bool t1ok = (rbase + 16) < n;
  const ushort* Ap[4] = {A0, A1, A2, A3};
  f32x4 acc[2][CT];
#pragma unroll
  for (int t = 0; t < 2; ++t)
#pragma unroll
    for (int c = 0; c < CT; ++c) acc[t][c] = (f32x4){0.f, 0.f, 0.f, 0.f};
  size_t aoff = (size_t)(rbase + (lane & 15)) * 128 + (lane >> 4) * 8;
#pragma unroll
  for (int k = 0; k < 4; ++k) {
    const ushort* A = Ap[k] + aoff;
#pragma unroll
    for (int kk = 0; kk < 4; ++kk) {
      short8 a0 = *reinterpret_cast<const short8*>(A + kk * 32);
      short8 a1 = {};
      if (t1ok) a1 = *reinterpret_cast<const short8*>(A + 16 * 128 + kk * 32);
      const ushort* B = pw + ((size_t)((k * 4 + kk) * CT) * 64 + lane) * 8;
#pragma unroll
      for (int c = 0; c < CT; ++c) {
        short8 b = *reinterpret_cast<const short8*>(B + (size_t)c * 64 * 8);
        acc[0][c] = __builtin_amdgcn_mfma_f32_16x16x32_bf16(a0, b, acc[0][c], 0, 0, 0);
        acc[1][c] = __builtin_amdgcn_mfma_f32_16x16x32_bf16(a1, b, acc[1][c], 0, 0, 0);
      }
    }
  }
  int colb = lane & 15;
  int rsub = (lane >> 4) * 4;
#pragma unroll
  for (int t = 0; t < 2; ++t) {
    int row0 = rbase + t * 16;
    if (row0 >= n) continue;
#pragma unroll
    for (int c = 0; c < CT; ++c) {
      int col = c * 16 + colb;
      float bv = bias[col];
#pragma unroll
      for (int r = 0; r < 4; ++r) {
        int row = row0 + rsub + r;
        float v = acc[t][c][r] + bv;
        if (RELU) v = fmaxf(v, 0.f);
        outb[(size_t)row * FOUT + col] = f2b(v);
      }
    }
  }
}

// ================= MFMA GEMM, layer 2: C = H @ Wc, output 4 x [n,64] bf16 =================
// Single A [n,128]; K=128 (kk=0..3); CT=16 (256 cols). 1 row-tile of 16 per wave.

__global__ __launch_bounds__(128) void mfma_gemmH_kernel(
    const ushort* __restrict__ A, const ushort* __restrict__ pw,
    ushort* __restrict__ C, int n) {
  constexpr int CT = 16;
  int wid = threadIdx.x >> 6;
  int lane = threadIdx.x & 63;
  int row0 = (blockIdx.x * 2 + wid) * 16;
  if (row0 >= n) return;
  f32x4 acc[CT];
#pragma unroll
  for (int c = 0; c < CT; ++c) acc[c] = (f32x4){0.f, 0.f, 0.f, 0.f};
  size_t aoff = (size_t)(row0 + (lane & 15)) * 128 + (lane >> 4) * 8;
#pragma unroll
  for (int kk = 0; kk < 4; ++kk) {
    short8 a = *reinterpret_cast<const short8*>(A + aoff + kk * 32);
    const ushort* B = pw + ((size_t)(kk * CT) * 64 + lane) * 8;
#pragma unroll
    for (int c = 0; c < CT; ++c) {
      short8 b = *reinterpret_cast<const short8*>(B + (size_t)c * 64 * 8);
      acc[c] = __builtin_amdgcn_mfma_f32_16x16x32_bf16(a, b, acc[c], 0, 0, 0);
    }
  }
  int colb = lane & 15;
  int rsub = (lane >> 4) * 4;
#pragma unroll
  for (int c = 0; c < CT; ++c) {
    int col = c * 16 + colb;
    int kb = col >> 6, wc = col & 63;
#pragma unroll
    for (int r = 0; r < 4; ++r) {
      int row = row0 + rsub + r;
      C[((size_t)kb * n + row) * 64 + wc] = f2b(acc[c][r]);
    }
  }
}

// ================= row log-softmax + bias (in-place fp32 [n,64]) =================

__global__ __launch_bounds__(256) void lsm_kernel(float* __restrict__ io,
                                                  const float* __restrict__ bias, int n) {
  int row = blockIdx.x * 4 + (threadIdx.x >> 6);
  if (row >= n) return;
  int lane = threadIdx.x & 63;
  size_t idx = (size_t)row * 64 + lane;
  float v = io[idx] + bias[lane];
  float m = v;
#pragma unroll
  for (int off = 32; off > 0; off >>= 1) m = fmaxf(m, __shfl_xor(m, off, 64));
  float ex = __expf(v - m);
  float s = ex;
#pragma unroll
  for (int off = 32; off > 0; off >>= 1) s += __shfl_xor(s, off, 64);
  io[idx] = (v - m) - logf(s);
}

// ================= launcher =================

extern "C" void kernel_launch(void* const* d_in, const int* in_sizes, int n_in,
                              void* d_out, int out_size, void* d_ws, size_t ws_size,
                              hipStream_t stream) {
  const float* x  = (const float*)d_in[0];
  const int*   ei = (const int*)d_in[1];
  const float* W1 = (const float*)d_in[2];
  const float* b1 = (const float*)d_in[3];
  const float* W2 = (const float*)d_in[4];
  const float* b2 = (const float*)d_in[5];
  float* out = (float*)d_out;

  const int N = in_sizes[0] / N_IN;
  const int E = in_sizes[1] / 2;
  const int NB = (N + 255) / 256;

  char* base = (char*)d_ws;
  size_t off = 0;
  auto alloc = [&](size_t bytes) -> void* {
    void* p = base + off;
    off = (off + bytes + 255) & ~(size_t)255;
    return p;
  };
  int*    deg    = (int*)alloc((size_t)N * 4);
  int*    rowptr = (int*)alloc((size_t)(N + 1) * 4);
  int*    cursor = (int*)alloc((size_t)N * 4);
  int*    bsum   = (int*)alloc((size_t)NB * 4);
  int2*   ew     = (int2*)alloc((size_t)E * 8);
  float*  dis    = (float*)alloc((size_t)N * 4);
  size_t  fsz    = (size_t)N * N_IN * 2;
  ushort* S1 = (ushort*)alloc(fsz);
  ushort* S2 = (ushort*)alloc(fsz);
  ushort* S3 = (ushort*)alloc(fsz);
  ushort* S4 = (ushort*)alloc(fsz);
  ushort* S5 = (ushort*)alloc(fsz);
  ushort* CB = (ushort*)alloc((size_t)4 * N * N_OUT * 2);   // C0..C3, each [N,64]
  ushort* pw1 = (ushort*)alloc((size_t)4 * N_IN * N_HID * 2);
  ushort* pw2 = (ushort*)alloc((size_t)N_HID * 4 * N_OUT * 2);

  ushort *xb = S1, *T1 = S2, *T2 = S3, *T3 = S4, *H = S5;
  ushort *I2 = S2, *I3 = S3;            // layer-2 chain reuses T1/T2 regions
  ushort *C0 = CB, *C1 = CB + (size_t)N * 64, *C2 = CB + (size_t)2 * N * 64,
         *C3 = CB + (size_t)3 * N * 64;

  hipMemsetAsync(deg, 0, (size_t)N * 4, stream);
  count_deg_kernel<<<(E + 255) / 256, 256, 0, stream>>>(ei, deg, E);
  scanA_kernel<<<NB, 256, 0, stream>>>(deg, bsum, N);
  scanB_kernel<<<1, 256, 0, stream>>>(bsum, NB);
  scanC_kernel<<<NB, 256, 0, stream>>>(deg, bsum, rowptr, dis, N);
  hipMemcpyAsync(cursor, rowptr, (size_t)N * 4, hipMemcpyDeviceToDevice, stream);
  fill_csr_kernel<<<(E + 255) / 256, 256, 0, stream>>>(ei, cursor, ew, dis, E);

  int n4 = N * N_IN / 4;
  cvt_bf16_kernel<<<(n4 + 255) / 256, 256, 0, stream>>>(x, xb, n4);
  pack_w_kernel<N_HID><<<(4 * 4 * (N_HID / 16) * 64 + 255) / 256, 256, 0, stream>>>(W1, pw1);
  pack_w2c_kernel<<<(4 * 16 * 64 + 255) / 256, 256, 0, stream>>>(W2, pw2);

  int pgrid = (N + 7) / 8;
  int ggrid = (N + 63) / 64;
  int ggrid2 = (N + 31) / 32;
  // ---- layer 1 (unchanged R7 structure) ----
  prop_kernel<<<pgrid, 256, 0, stream>>>(xb, nullptr, T1, rowptr, ew, dis, N);
  prop_kernel<<<pgrid, 256, 0, stream>>>(T1, xb,      T2, rowptr, ew, dis, N);
  prop_kernel<<<pgrid, 256, 0, stream>>>(T2, T1,      T3, rowptr, ew, dis, N);
  mfma_gemm_kernel<N_HID, true><<<ggrid, 128, 0, stream>>>(
      xb, T1, T2, T3, pw1, b1, H, N);
  // ---- layer 2: Horner form, 64-wide props ----
  // C = H @ [W0-W2 | W1-3W3 | 2W2 | 4W3]
  mfma_gemmH_kernel<<<ggrid2, 128, 0, stream>>>(H, pw2, CB, N);
  // I2 = C2 + L*C3 ; I3 = C1 + L*I2 ; out = C0 + L*I3 (fp32)
  prop64_kernel<false><<<pgrid, 256, 0, stream>>>(C3, C2, I2, rowptr, ew, dis, N);
  prop64_kernel<false><<<pgrid, 256, 0, stream>>>(I2, C1, I3, rowptr, ew, dis, N);
  prop64_kernel<true ><<<pgrid, 256, 0, stream>>>(I3, C0, out, rowptr, ew, dis, N);
  // log-softmax (+bias) in-place
  lsm_kernel<<<(N + 3) / 4, 256, 0, stream>>>(out, b2, N);
}

// Round 10
// 319.729 us; speedup vs baseline: 1.6610x; 1.0893x over previous
//
#include <hip/hip_runtime.h>
#include <cstddef>
#include <cstdint>

#define N_IN  128
#define N_HID 128
#define N_OUT 64
#define CHUNK 4096        // edges per binA block
#define BSPAN 512         // nodes per bucket (nbuck = ceil(N/512) <= 256 supported)

typedef unsigned short ushort;
typedef unsigned int uint;
using short8 = __attribute__((ext_vector_type(8))) short;
using f32x4  = __attribute__((ext_vector_type(4))) float;

__device__ __forceinline__ ushort f2b(float f) {
  uint u = __builtin_bit_cast(uint, f);
  uint r = (u + 0x7fffu + ((u >> 16) & 1u)) >> 16;   // RNE
  return (ushort)r;
}
__device__ __forceinline__ float b2f(ushort u) {
  return __builtin_bit_cast(float, ((uint)u) << 16);
}

// ================= CSR build =================

__global__ void count_deg_kernel(const int* __restrict__ ei, int* __restrict__ deg, int E) {
  int e = blockIdx.x * 256 + threadIdx.x;
  if (e < E) atomicAdd(&deg[ei[E + e]], 1);
}

__global__ __launch_bounds__(256) void scanA_kernel(const int* __restrict__ deg,
                                                    int* __restrict__ bsum, int n) {
  int i = blockIdx.x * 256 + threadIdx.x;
  int v = (i < n) ? deg[i] : 0;
#pragma unroll
  for (int off = 32; off > 0; off >>= 1) v += __shfl_xor(v, off, 64);
  __shared__ int ws[4];
  int lane = threadIdx.x & 63, wid = threadIdx.x >> 6;
  if (lane == 0) ws[wid] = v;
  __syncthreads();
  if (threadIdx.x == 0) bsum[blockIdx.x] = ws[0] + ws[1] + ws[2] + ws[3];
}

__global__ __launch_bounds__(256) void scanB_kernel(int* __restrict__ bsum, int nb) {
  int tid = threadIdx.x;
  int c = (nb + 255) >> 8;
  int st = tid * c, en = min(st + c, nb);
  int s = 0;
  for (int i = st; i < en; ++i) s += bsum[i];
  int lane = tid & 63, wid = tid >> 6;
  int incl = s;
#pragma unroll
  for (int off = 1; off < 64; off <<= 1) {
    int t = __shfl_up(incl, off, 64);
    if (lane >= off) incl += t;
  }
  __shared__ int ws[4];
  if (lane == 63) ws[wid] = incl;
  __syncthreads();
  int wbase = 0;
  for (int w = 0; w < wid; ++w) wbase += ws[w];
  int ex = wbase + incl - s;
  for (int i = st; i < en; ++i) {
    int d = bsum[i];
    bsum[i] = ex;
    ex += d;
  }
}

__global__ __launch_bounds__(256) void scanC_kernel(const int* __restrict__ deg,
                                                    const int* __restrict__ bsum,
                                                    int* __restrict__ rowptr,
                                                    float* __restrict__ dis, int n) {
  int i = blockIdx.x * 256 + threadIdx.x;
  int d = (i < n) ? deg[i] : 0;
  int lane = threadIdx.x & 63, wid = threadIdx.x >> 6;
  int incl = d;
#pragma unroll
  for (int off = 1; off < 64; off <<= 1) {
    int t = __shfl_up(incl, off, 64);
    if (lane >= off) incl += t;
  }
  __shared__ int ws[4];
  if (lane == 63) ws[wid] = incl;
  __syncthreads();
  int wbase = 0;
  for (int w = 0; w < wid; ++w) wbase += ws[w];
  int ex = bsum[blockIdx.x] + wbase + incl - d;
  if (i < n) {
    rowptr[i] = ex;
    dis[i] = (d > 0) ? rsqrtf((float)d) : 0.0f;
    if (i == n - 1) rowptr[n] = ex + d;
  }
}

__global__ void gcinit_kernel(const int* __restrict__ rowptr, int* __restrict__ gcur,
                              int nbuck, int n) {
  int b = blockIdx.x * 256 + threadIdx.x;
  if (b < nbuck) gcur[b] = rowptr[min(b << 9, n)];
}

// Phase A: single pass over edges; LDS-bin by 512-node bucket; one global cursor
// atomic per (block,bucket); contiguous flush of 4B packed (src | dlocal<<17).
__global__ __launch_bounds__(256) void binA_kernel(const int* __restrict__ ei,
                                                   int* __restrict__ gcur,
                                                   uint* __restrict__ stage4,
                                                   int E, int nbuck) {
  __shared__ int cnt[256], lstart[256], off[256], gbase[256];
  __shared__ uint stg[CHUNK];
  __shared__ unsigned char bos[CHUNK];
  int e0 = blockIdx.x * CHUNK;
  int tid = threadIdx.x;
  for (int i = tid; i < nbuck; i += 256) cnt[i] = 0;
  __syncthreads();
  int s[16], d[16];
#pragma unroll
  for (int j = 0; j < 16; ++j) {
    int e = e0 + tid + j * 256;
    s[j] = -1;
    if (e < E) {
      s[j] = ei[e];
      d[j] = ei[E + e];
      atomicAdd(&cnt[d[j] >> 9], 1);
    }
  }
  __syncthreads();
  if (tid == 0) {
    int run = 0;
    for (int b = 0; b < nbuck; ++b) { lstart[b] = run; run += cnt[b]; }
  }
  __syncthreads();
  for (int i = tid; i < nbuck; i += 256) off[i] = lstart[i];
  __syncthreads();
#pragma unroll
  for (int j = 0; j < 16; ++j) {
    if (s[j] >= 0) {
      int b = d[j] >> 9;
      int pos = atomicAdd(&off[b], 1);
      stg[pos] = (uint)s[j] | ((uint)(d[j] & (BSPAN - 1)) << 17);
      bos[pos] = (unsigned char)b;
    }
  }
  __syncthreads();
  for (int b = tid; b < nbuck; b += 256)
    if (cnt[b] > 0) gbase[b] = atomicAdd(&gcur[b], cnt[b]);
  __syncthreads();
  int total = min(CHUNK, E - e0);
  for (int i = tid; i < total; i += 256) {
    int b = bos[i];
    stage4[gbase[b] + (i - lstart[b])] = stg[i];
  }
}

// Phase B: one block per bucket; LDS cursors; fine scatter confined to the
// bucket's contiguous ew region (single-XCD L2 assembles lines).
__global__ __launch_bounds__(256) void binB_kernel(const uint* __restrict__ stage4,
                                                   const int* __restrict__ rowptr,
                                                   const float* __restrict__ dis,
                                                   int2* __restrict__ ew, int n) {
  __shared__ int cur[BSPAN];
  int base = blockIdx.x << 9;
  int hi = min(base + BSPAN, n);
  for (int l = threadIdx.x; l < hi - base; l += 256) cur[l] = rowptr[base + l];
  __syncthreads();
  int estart = rowptr[base], eend = rowptr[hi];
  for (int t = estart + (int)threadIdx.x; t < eend; t += 256) {
    uint v = stage4[t];
    int src = v & 0x1FFFF;
    int dl = v >> 17;
    int pos = atomicAdd(&cur[dl], 1);
    ew[pos] = make_int2(src, __builtin_bit_cast(int, dis[src]));
  }
}

// ================= fp32 -> bf16 convert (row-major) =================

__global__ __launch_bounds__(256) void cvt_bf16_kernel(const float* __restrict__ in,
                                                       ushort* __restrict__ xb, int n4) {
  int i = blockIdx.x * 256 + threadIdx.x;
  if (i >= n4) return;
  float4 v = reinterpret_cast<const float4*>(in)[i];
  ushort4 o;
  o.x = f2b(v.x); o.y = f2b(v.y); o.z = f2b(v.z); o.w = f2b(v.w);
  reinterpret_cast<ushort4*>(xb)[i] = o;
}

// ================= W1 pack into MFMA B-fragment order =================
// pw[(k*4+kk)*CT + ct][lane][j] = W[k][kk*32 + (lane>>4)*8 + j][ct*16 + (lane&15)]

template <int FOUT>
__global__ __launch_bounds__(256) void pack_w_kernel(const float* __restrict__ W,
                                                     ushort* __restrict__ pw) {
  constexpr int CT = FOUT / 16;
  int t = blockIdx.x * 256 + threadIdx.x;
  if (t >= 4 * 4 * CT * 64) return;
  int lane = t & 63;
  int g = t >> 6;
  int ct = g % CT;
  int kk = (g / CT) % 4;
  int k  = g / (CT * 4);
  int col = ct * 16 + (lane & 15);
  int krow0 = kk * 32 + (lane >> 4) * 8;
  ushort* dst = pw + (size_t)t * 8;
  const float* src = W + ((size_t)k * 128 + krow0) * FOUT + col;
#pragma unroll
  for (int j = 0; j < 8; ++j) dst[j] = f2b(src[(size_t)j * FOUT]);
}

// ================= W2 combined pack (Horner coefficients) =================
// Wc[128][256] blocks: [W0-W2 | W1-3W3 | 2W2 | 4W3]; frag layout as above, K=128.

__global__ __launch_bounds__(256) void pack_w2c_kernel(const float* __restrict__ W,
                                                       ushort* __restrict__ pw) {
  int t = blockIdx.x * 256 + threadIdx.x;
  if (t >= 4 * 16 * 64) return;       // kk (4) x ct (16) x lane (64)
  int lane = t & 63;
  int g = t >> 6;
  int ct = g & 15;
  int kk = g >> 4;
  int col = ct * 16 + (lane & 15);    // 0..255
  int kb = col >> 6;                  // which combo block
  int cc = col & 63;
  int krow0 = kk * 32 + (lane >> 4) * 8;
  ushort* dst = pw + (size_t)t * 8;
#pragma unroll
  for (int j = 0; j < 8; ++j) {
    int r = krow0 + j;
    float w0 = W[((size_t)0 * 128 + r) * 64 + cc];
    float w1 = W[((size_t)1 * 128 + r) * 64 + cc];
    float w2 = W[((size_t)2 * 128 + r) * 64 + cc];
    float w3 = W[((size_t)3 * 128 + r) * 64 + cc];
    float v = (kb == 0) ? (w0 - w2)
            : (kb == 1) ? (w1 - 3.f * w3)
            : (kb == 2) ? (2.f * w2)
                        : (4.f * w3);
    dst[j] = f2b(v);
  }
}

// ================= sparse propagation, 128-wide (layer 1) =================

__global__ __launch_bounds__(256) void prop_kernel(
    const ushort* __restrict__ in, const ushort* __restrict__ sub,
    ushort* __restrict__ out,
    const int* __restrict__ rowptr, const int2* __restrict__ ew,
    const float* __restrict__ dis, int n) {
  int node = blockIdx.x * 8 + (threadIdx.x >> 5);
  if (node >= n) return;
  int hl = threadIdx.x & 31;
  int s = rowptr[node];
  int e = rowptr[node + 1];
  size_t ro = ((size_t)node << 7) + (hl << 2);
  uint2 sv = make_uint2(0u, 0u);
  if (sub != nullptr) sv = *reinterpret_cast<const uint2*>(sub + ro);
  float a0 = 0.f, a1 = 0.f, a2 = 0.f, a3 = 0.f;
  for (int i = s; i < e; i += 8) {
    int2 p[8];
#pragma unroll
    for (int j = 0; j < 8; ++j) {
      int idx = i + j;
      p[j] = ew[idx < e ? idx : e - 1];
    }
    uint2 v[8];
#pragma unroll
    for (int j = 0; j < 8; ++j)
      v[j] = *reinterpret_cast<const uint2*>(in + ((size_t)p[j].x << 7) + (hl << 2));
#pragma unroll
    for (int j = 0; j < 8; ++j) {
      float w = (i + j < e) ? __builtin_bit_cast(float, p[j].y) : 0.f;
      a0 = fmaf(w, b2f((ushort)v[j].x), a0);
      a1 = fmaf(w, b2f((ushort)(v[j].x >> 16)), a1);
      a2 = fmaf(w, b2f((ushort)v[j].y), a2);
      a3 = fmaf(w, b2f((ushort)(v[j].y >> 16)), a3);
    }
  }
  float sc = -dis[node];
  float r0, r1, r2, r3;
  if (sub != nullptr) {
    float t = 2.f * sc;
    r0 = fmaf(t, a0, -b2f((ushort)sv.x));
    r1 = fmaf(t, a1, -b2f((ushort)(sv.x >> 16)));
    r2 = fmaf(t, a2, -b2f((ushort)sv.y));
    r3 = fmaf(t, a3, -b2f((ushort)(sv.y >> 16)));
  } else {
    r0 = sc * a0; r1 = sc * a1; r2 = sc * a2; r3 = sc * a3;
  }
  uint2 o;
  o.x = (uint)f2b(r0) | ((uint)f2b(r1) << 16);
  o.y = (uint)f2b(r2) | ((uint)f2b(r3) << 16);
  *reinterpret_cast<uint2*>(out + ro) = o;
}

// ================= sparse propagation, 64-wide (layer-2 Horner chain) =================
// r_i = -dis_i*sum + aux_i. F32OUT: fused +bias, row log-softmax (32-lane half-wave
// holds the full 64-col row; shfl_xor <=16 stays within each half), fp32 out.

template <bool F32OUT>
__global__ __launch_bounds__(256) void prop64_kernel(
    const ushort* __restrict__ in, const ushort* __restrict__ aux,
    void* __restrict__ outv,
    const int* __restrict__ rowptr, const int2* __restrict__ ew,
    const float* __restrict__ dis, const float* __restrict__ bias, int n) {
  int node = blockIdx.x * 8 + (threadIdx.x >> 5);
  if (node >= n) return;
  int hl = threadIdx.x & 31;
  int s = rowptr[node];
  int e = rowptr[node + 1];
  float a0 = 0.f, a1 = 0.f;
  for (int i = s; i < e; i += 8) {
    int2 p[8];
#pragma unroll
    for (int j = 0; j < 8; ++j) {
      int idx = i + j;
      p[j] = ew[idx < e ? idx : e - 1];
    }
    uint v[8];
#pragma unroll
    for (int j = 0; j < 8; ++j)
      v[j] = *reinterpret_cast<const uint*>(in + ((size_t)p[j].x << 6) + (hl << 1));
#pragma unroll
    for (int j = 0; j < 8; ++j) {
      float w = (i + j < e) ? __builtin_bit_cast(float, p[j].y) : 0.f;
      a0 = fmaf(w, b2f((ushort)v[j]), a0);
      a1 = fmaf(w, b2f((ushort)(v[j] >> 16)), a1);
    }
  }
  float sc = -dis[node];
  size_t ro = ((size_t)node << 6) + (hl << 1);
  uint av = *reinterpret_cast<const uint*>(aux + ro);
  float r0 = fmaf(sc, a0, b2f((ushort)av));
  float r1 = fmaf(sc, a1, b2f((ushort)(av >> 16)));
  if (F32OUT) {
    r0 += bias[hl << 1];
    r1 += bias[(hl << 1) + 1];
    float m = fmaxf(r0, r1);
#pragma unroll
    for (int o = 16; o > 0; o >>= 1) m = fmaxf(m, __shfl_xor(m, o, 64));
    float sum = __expf(r0 - m) + __expf(r1 - m);
#pragma unroll
    for (int o = 16; o > 0; o >>= 1) sum += __shfl_xor(sum, o, 64);
    float ls = logf(sum) + m;
    *reinterpret_cast<float2*>(reinterpret_cast<float*>(outv) + ro) =
        make_float2(r0 - ls, r1 - ls);
  } else {
    uint o = (uint)f2b(r0) | ((uint)f2b(r1) << 16);
    *reinterpret_cast<uint*>(reinterpret_cast<ushort*>(outv) + ro) = o;
  }
}

// ================= MFMA GEMM, layer 1 (4 A's, FOUT=128, relu, bf16 out) =================

template <int FOUT, bool RELU>
__global__ __launch_bounds__(128) void mfma_gemm_kernel(
    const ushort* __restrict__ A0, const ushort* __restrict__ A1,
    const ushort* __restrict__ A2, const ushort* __restrict__ A3,
    const ushort* __restrict__ pw, const float* __restrict__ bias,
    ushort* __restrict__ outb, int n) {
  constexpr int CT = FOUT / 16;
  int wid = threadIdx.x >> 6;
  int lane = threadIdx.x & 63;
  int rbase = (blockIdx.x * 2 + wid) * 32;
  if (rbase >= n) return;                 // n % 16 == 0
  bool t1ok = (rbase + 16) < n;
  const ushort* Ap[4] = {A0, A1, A2, A3};
  f32x4 acc[2][CT];
#pragma unroll
  for (int t = 0; t < 2; ++t)
#pragma unroll
    for (int c = 0; c < CT; ++c) acc[t][c] = (f32x4){0.f, 0.f, 0.f, 0.f};
  size_t aoff = (size_t)(rbase + (lane & 15)) * 128 + (lane >> 4) * 8;
#pragma unroll
  for (int k = 0; k < 4; ++k) {
    const ushort* A = Ap[k] + aoff;
#pragma unroll
    for (int kk = 0; kk < 4; ++kk) {
      short8 a0 = *reinterpret_cast<const short8*>(A + kk * 32);
      short8 a1 = {};
      if (t1ok) a1 = *reinterpret_cast<const short8*>(A + 16 * 128 + kk * 32);
      const ushort* B = pw + ((size_t)((k * 4 + kk) * CT) * 64 + lane) * 8;
#pragma unroll
      for (int c = 0; c < CT; ++c) {
        short8 b = *reinterpret_cast<const short8*>(B + (size_t)c * 64 * 8);
        acc[0][c] = __builtin_amdgcn_mfma_f32_16x16x32_bf16(a0, b, acc[0][c], 0, 0, 0);
        acc[1][c] = __builtin_amdgcn_mfma_f32_16x16x32_bf16(a1, b, acc[1][c], 0, 0, 0);
      }
    }
  }
  int colb = lane & 15;
  int rsub = (lane >> 4) * 4;
#pragma unroll
  for (int t = 0; t < 2; ++t) {
    int row0 = rbase + t * 16;
    if (row0 >= n) continue;
#pragma unroll
    for (int c = 0; c < CT; ++c) {
      int col = c * 16 + colb;
      float bv = bias[col];
#pragma unroll
      for (int r = 0; r < 4; ++r) {
        int row = row0 + rsub + r;
        float v = acc[t][c][r] + bv;
        if (RELU) v = fmaxf(v, 0.f);
        outb[(size_t)row * FOUT + col] = f2b(v);
      }
    }
  }
}

// ================= MFMA GEMM, layer 2: C = H @ Wc, output 4 x [n,64] bf16 =================

__global__ __launch_bounds__(128) void mfma_gemmH_kernel(
    const ushort* __restrict__ A, const ushort* __restrict__ pw,
    ushort* __restrict__ C, int n) {
  constexpr int CT = 16;
  int wid = threadIdx.x >> 6;
  int lane = threadIdx.x & 63;
  int row0 = (blockIdx.x * 2 + wid) * 16;
  if (row0 >= n) return;
  f32x4 acc[CT];
#pragma unroll
  for (int c = 0; c < CT; ++c) acc[c] = (f32x4){0.f, 0.f, 0.f, 0.f};
  size_t aoff = (size_t)(row0 + (lane & 15)) * 128 + (lane >> 4) * 8;
#pragma unroll
  for (int kk = 0; kk < 4; ++kk) {
    short8 a = *reinterpret_cast<const short8*>(A + aoff + kk * 32);
    const ushort* B = pw + ((size_t)(kk * CT) * 64 + lane) * 8;
#pragma unroll
    for (int c = 0; c < CT; ++c) {
      short8 b = *reinterpret_cast<const short8*>(B + (size_t)c * 64 * 8);
      acc[c] = __builtin_amdgcn_mfma_f32_16x16x32_bf16(a, b, acc[c], 0, 0, 0);
    }
  }
  int colb = lane & 15;
  int rsub = (lane >> 4) * 4;
#pragma unroll
  for (int c = 0; c < CT; ++c) {
    int col = c * 16 + colb;
    int kb = col >> 6, wc = col & 63;
#pragma unroll
    for (int r = 0; r < 4; ++r) {
      int row = row0 + rsub + r;
      C[((size_t)kb * n + row) * 64 + wc] = f2b(acc[c][r]);
    }
  }
}

// ================= launcher =================

extern "C" void kernel_launch(void* const* d_in, const int* in_sizes, int n_in,
                              void* d_out, int out_size, void* d_ws, size_t ws_size,
                              hipStream_t stream) {
  const float* x  = (const float*)d_in[0];
  const int*   ei = (const int*)d_in[1];
  const float* W1 = (const float*)d_in[2];
  const float* b1 = (const float*)d_in[3];
  const float* W2 = (const float*)d_in[4];
  const float* b2 = (const float*)d_in[5];
  float* out = (float*)d_out;

  const int N = in_sizes[0] / N_IN;
  const int E = in_sizes[1] / 2;
  const int NB = (N + 255) / 256;
  const int NBUCK = (N + BSPAN - 1) / BSPAN;

  char* base = (char*)d_ws;
  size_t off = 0;
  auto alloc = [&](size_t bytes) -> void* {
    void* p = base + off;
    off = (off + bytes + 255) & ~(size_t)255;
    return p;
  };
  int*    deg    = (int*)alloc((size_t)N * 4);
  int*    rowptr = (int*)alloc((size_t)(N + 1) * 4);
  int*    bsum   = (int*)alloc((size_t)NB * 4);
  int*    gcur   = (int*)alloc((size_t)NBUCK * 4);
  uint*   stage4 = (uint*)alloc((size_t)E * 4);
  int2*   ew     = (int2*)alloc((size_t)E * 8);
  float*  dis    = (float*)alloc((size_t)N * 4);
  size_t  fsz    = (size_t)N * N_IN * 2;
  ushort* S1 = (ushort*)alloc(fsz);
  ushort* S2 = (ushort*)alloc(fsz);
  ushort* S3 = (ushort*)alloc(fsz);
  ushort* S4 = (ushort*)alloc(fsz);
  ushort* S5 = (ushort*)alloc(fsz);
  ushort* CB = (ushort*)alloc((size_t)4 * N * N_OUT * 2);   // C0..C3, each [N,64]
  ushort* pw1 = (ushort*)alloc((size_t)4 * N_IN * N_HID * 2);
  ushort* pw2 = (ushort*)alloc((size_t)N_HID * 4 * N_OUT * 2);

  ushort *xb = S1, *T1 = S2, *T2 = S3, *T3 = S4, *H = S5;
  ushort *I2 = S2, *I3 = S3;            // layer-2 chain reuses T1/T2 regions
  ushort *C0 = CB, *C1 = CB + (size_t)N * 64, *C2 = CB + (size_t)2 * N * 64,
         *C3 = CB + (size_t)3 * N * 64;

  hipMemsetAsync(deg, 0, (size_t)N * 4, stream);
  count_deg_kernel<<<(E + 255) / 256, 256, 0, stream>>>(ei, deg, E);
  scanA_kernel<<<NB, 256, 0, stream>>>(deg, bsum, N);
  scanB_kernel<<<1, 256, 0, stream>>>(bsum, NB);
  scanC_kernel<<<NB, 256, 0, stream>>>(deg, bsum, rowptr, dis, N);
  gcinit_kernel<<<(NBUCK + 255) / 256, 256, 0, stream>>>(rowptr, gcur, NBUCK, N);
  binA_kernel<<<(E + CHUNK - 1) / CHUNK, 256, 0, stream>>>(ei, gcur, stage4, E, NBUCK);
  binB_kernel<<<NBUCK, 256, 0, stream>>>(stage4, rowptr, dis, ew, N);

  int n4 = N * N_IN / 4;
  cvt_bf16_kernel<<<(n4 + 255) / 256, 256, 0, stream>>>(x, xb, n4);
  pack_w_kernel<N_HID><<<(4 * 4 * (N_HID / 16) * 64 + 255) / 256, 256, 0, stream>>>(W1, pw1);
  pack_w2c_kernel<<<(4 * 16 * 64 + 255) / 256, 256, 0, stream>>>(W2, pw2);

  int pgrid = (N + 7) / 8;
  int ggrid = (N + 63) / 64;
  int ggrid2 = (N + 31) / 32;
  // ---- layer 1 ----
  prop_kernel<<<pgrid, 256, 0, stream>>>(xb, nullptr, T1, rowptr, ew, dis, N);
  prop_kernel<<<pgrid, 256, 0, stream>>>(T1, xb,      T2, rowptr, ew, dis, N);
  prop_kernel<<<pgrid, 256, 0, stream>>>(T2, T1,      T3, rowptr, ew, dis, N);
  mfma_gemm_kernel<N_HID, true><<<ggrid, 128, 0, stream>>>(
      xb, T1, T2, T3, pw1, b1, H, N);
  // ---- layer 2: Horner form, 64-wide props ----
  mfma_gemmH_kernel<<<ggrid2, 128, 0, stream>>>(H, pw2, CB, N);
  prop64_kernel<false><<<pgrid, 256, 0, stream>>>(C3, C2, I2, rowptr, ew, dis, nullptr, N);
  prop64_kernel<false><<<pgrid, 256, 0, stream>>>(I2, C1, I3, rowptr, ew, dis, nullptr, N);
  prop64_kernel<true ><<<pgrid, 256, 0, stream>>>(I3, C0, out, rowptr, ew, dis, b2, N);
}